// Round 1
// baseline (471.624 us; speedup 1.0000x reference)
//
#include <hip/hip_runtime.h>

#define NUM_CN   25000
#define NUM_VN   50000
#define NUM_E    200000
#define D_EMBED  16
#define D_HIDDEN 32
#define D_MSG    16
#define BATCH    16

// ---------------------------------------------------------------------------
// Workspace layout (int units) — 54.41 MB total (proven available in R2-R4):
#define WS_IDS_X   0           // 200000  (stores FROM node ids, CSR order)
#define WS_IDS_Z   200000      // 200000
#define WS_OFF_X   400000      // 50001
#define WS_OFF_Z   450001      // 50001
#define WS_CNT_X   500002      // 50000
#define WS_CNT_Z   550002      // 50000
#define WS_CUR_X   600002      // 50000 -> bits_x after fill
#define WS_CUR_Z   650002      // 50000 -> bits_z after fill
#define WS_INCL_X  700002      // 51200
#define WS_INCL_Z  751202      // 51200
#define WS_PSUM    802402      // 128
#define WS_BASE    802530      // 128
#define WS_A1X     802816      // 6400000 ints = 25.6 MB bf16
#define WS_A1Z     7202816     // 6400000
#define SCAN_CHUNKS 49

__global__ __launch_bounds__(256) void hist_kernel(
    const int* __restrict__ ti_x, const int* __restrict__ ti_z,
    int* __restrict__ cnt_x, int* __restrict__ cnt_z)
{
    int e = blockIdx.x * 256 + threadIdx.x;
    if (e >= NUM_E) return;
    atomicAdd(&cnt_x[ti_x[e]], 1);
    atomicAdd(&cnt_z[ti_z[e]], 1);
}

__global__ __launch_bounds__(1024) void scan1_kernel(
    const int* __restrict__ cnt_x, const int* __restrict__ cnt_z,
    int* __restrict__ incl_x, int* __restrict__ incl_z,
    int* __restrict__ psum)
{
    __shared__ int s[1024];
    const int ch  = blockIdx.y;
    const int blk = blockIdx.x;
    const int t   = threadIdx.x;
    const int gid = blk * 1024 + t;
    const int* cnt  = ch ? cnt_z  : cnt_x;
    int*       incl = ch ? incl_z : incl_x;
    int v = (gid < NUM_VN) ? cnt[gid] : 0;
    s[t] = v;
    __syncthreads();
#pragma unroll
    for (int d = 1; d < 1024; d <<= 1) {
        int x = 0;
        if (t >= d) x = s[t - d];
        __syncthreads();
        if (t >= d) s[t] += x;
        __syncthreads();
    }
    incl[gid] = s[t];
    if (t == 1023) psum[ch * 64 + blk] = s[1023];
}

__global__ void scan2_kernel(const int* __restrict__ psum, int* __restrict__ base)
{
    int ch = threadIdx.x;
    if (ch >= 2) return;
    int run = 0;
    for (int i = 0; i < SCAN_CHUNKS; ++i) {
        base[ch * 64 + i] = run;
        run += psum[ch * 64 + i];
    }
}

__global__ __launch_bounds__(1024) void scan3_kernel(
    const int* __restrict__ cnt_x, const int* __restrict__ cnt_z,
    const int* __restrict__ incl_x, const int* __restrict__ incl_z,
    const int* __restrict__ base,
    int* __restrict__ off_x, int* __restrict__ off_z,
    int* __restrict__ cur_x, int* __restrict__ cur_z)
{
    const int ch  = blockIdx.y;
    const int blk = blockIdx.x;
    const int t   = threadIdx.x;
    const int i   = blk * 1024 + t;
    if (i >= NUM_VN) return;
    const int* cnt  = ch ? cnt_z  : cnt_x;
    const int* incl = ch ? incl_z : incl_x;
    int*       off  = ch ? off_z  : off_x;
    int*       cur  = ch ? cur_z  : cur_x;
    int bs = base[ch * 64 + blk];
    int iv = incl[i];
    off[i + 1] = bs + iv;
    cur[i]     = bs + iv - cnt[i];
    if (i == 0) off[0] = 0;
}

// fill: CSR slot stores the FROM node id directly.
__global__ __launch_bounds__(256) void fill_kernel(
    const int* __restrict__ ti_x, const int* __restrict__ ti_z,
    const int* __restrict__ fi_x, const int* __restrict__ fi_z,
    int* __restrict__ cur_x, int* __restrict__ cur_z,
    int* __restrict__ ids_x, int* __restrict__ ids_z)
{
    int e = blockIdx.x * 256 + threadIdx.x;
    if (e >= NUM_E) return;
    int px = atomicAdd(&cur_x[ti_x[e]], 1);
    ids_x[px] = fi_x[e];
    int pz = atomicAdd(&cur_z[ti_z[e]], 1);
    ids_z[pz] = fi_z[e];
}

// syn bitmask: bits[cn] bit b = syn[b,cn]. Runs AFTER fill (targets dead cur_*).
__global__ __launch_bounds__(256) void pack_bits_kernel(
    const int* __restrict__ syn_x, const int* __restrict__ syn_z,
    unsigned* __restrict__ bits_x, unsigned* __restrict__ bits_z)
{
    int cn = blockIdx.x * 256 + threadIdx.x;
    if (cn >= NUM_CN) return;
    unsigned wx = 0, wz = 0;
#pragma unroll
    for (int b = 0; b < BATCH; ++b) {
        wx |= (unsigned)(syn_x[b * NUM_CN + cn] & 1) << b;
        wz |= (unsigned)(syn_z[b * NUM_CN + cn] & 1) << b;
    }
    bits_x[cn] = wx;
    bits_z[cn] = wz;
}

// ---------------------------------------------------------------------------
__device__ __forceinline__ unsigned pack_bf16(float a, float b) {
    unsigned ua = __float_as_uint(a); ua += 0x7fff + ((ua >> 16) & 1);
    unsigned ub = __float_as_uint(b); ub += 0x7fff + ((ub >> 16) & 1);
    return (ua >> 16) | (ub & 0xffff0000u);
}

// a1[ch][cn][b][32] = h_from[b,cn,:] @ W1[0:16,:]  bf16 lane-interleaved.
// MASK FOLDED IN: if syn[b,cn]==0, the row is written as bf16 -inf, so the
// gather-side relu(a1 + a2) == 0 reproduces mask*relu(...) with no per-edge
// mask load or fmaf-by-mask.
__global__ __launch_bounds__(256) void a1_kernel(
    const float* __restrict__ h_from_x, const float* __restrict__ h_from_z,
    const float* __restrict__ Wx1, const float* __restrict__ Wz1,
    const unsigned* __restrict__ bits_x, const unsigned* __restrict__ bits_z,
    uint4* __restrict__ a1x, uint4* __restrict__ a1z)
{
    int t = blockIdx.x * 256 + threadIdx.x;
    if (t >= NUM_CN * BATCH) return;
    const int ch = blockIdx.y;
    const int b  = t & 15;
    const int cn = t >> 4;
    const float* hsrc = (ch ? h_from_z : h_from_x) + ((size_t)b * NUM_CN + cn) * D_EMBED;
    const float* W1   = ch ? Wz1 : Wx1;
    const unsigned mw = (ch ? bits_z : bits_x)[cn];
    const bool on = (mw >> b) & 1u;
    uint4* dst = (ch ? a1z : a1x) + (size_t)cn * 64;

    float hf[D_EMBED];
#pragma unroll
    for (int i = 0; i < 4; ++i) {
        float4 v = ((const float4*)hsrc)[i];
        hf[4 * i + 0] = v.x; hf[4 * i + 1] = v.y;
        hf[4 * i + 2] = v.z; hf[4 * i + 3] = v.w;
    }
    float a[D_HIDDEN];
#pragma unroll
    for (int j = 0; j < D_HIDDEN; ++j) a[j] = 0.0f;
#pragma unroll
    for (int i = 0; i < D_EMBED; ++i) {
        const float fi = hf[i];
#pragma unroll
        for (int j = 0; j < D_HIDDEN; ++j)
            a[j] = fmaf(fi, W1[i * D_HIDDEN + j], a[j]);
    }
    unsigned u[16];
#pragma unroll
    for (int j = 0; j < 16; ++j)
        u[j] = on ? pack_bf16(a[2 * j], a[2 * j + 1]) : 0xFF80FF80u;
#pragma unroll
    for (int p = 0; p < 4; ++p) {
        uint4 q;
        q.x = u[4 * p + 0]; q.y = u[4 * p + 1];
        q.z = u[4 * p + 2]; q.w = u[4 * p + 3];
        dst[p * 16 + b] = q;
    }
}

// ---------------------------------------------------------------------------
// consume one edge's 64B a1 row (bf16 pairs) into hacc
__device__ __forceinline__ void consume_edge(
    const uint4 q0, const uint4 q1, const uint4 q2, const uint4 q3,
    const float2* __restrict__ act, float2* __restrict__ hacc)
{
    unsigned uu[16] = {q0.x, q0.y, q0.z, q0.w,
                       q1.x, q1.y, q1.z, q1.w,
                       q2.x, q2.y, q2.z, q2.w,
                       q3.x, q3.y, q3.z, q3.w};
#pragma unroll
    for (int p = 0; p < 16; ++p) {
        float lo = __uint_as_float(uu[p] << 16);
        float hi = __uint_as_float(uu[p] & 0xffff0000u);
        hacc[p].x += fmaxf(act[p].x + lo, 0.0f);
        hacc[p].y += fmaxf(act[p].y + hi, 0.0f);
    }
}

// One channel: a2 = ht @ W1[16:32]; hacc = sum_e relu(a1'[from] + a2)
// (mask is pre-folded into a1' as -inf rows); m = hacc @ W2 kept fp32.
// Edge loop processes 2 edges/iter for 2x memory-level parallelism.
__device__ __forceinline__ void channel_accum(
    const float* __restrict__ h_to_slot, int n, int b,
    const int* __restrict__ off, const int* __restrict__ ids,
    const uint4* __restrict__ a1,
    const float* __restrict__ W1, const float* __restrict__ W2,
    float* __restrict__ mout)
{
    // reload ht per channel: 4 cache-hit loads < 16 live registers
    float ht[D_EMBED];
#pragma unroll
    for (int i = 0; i < 4; ++i) {
        float4 v = ((const float4*)h_to_slot)[i];
        ht[4 * i + 0] = v.x; ht[4 * i + 1] = v.y;
        ht[4 * i + 2] = v.z; ht[4 * i + 3] = v.w;
    }
    float2 act[16];
#pragma unroll
    for (int p = 0; p < 16; ++p) { act[p].x = 0.0f; act[p].y = 0.0f; }
#pragma unroll
    for (int i = 0; i < D_EMBED; ++i) {
        const float hi = ht[i];
        const float* w = W1 + (D_EMBED + i) * D_HIDDEN;
#pragma unroll
        for (int p = 0; p < 16; ++p) {
            act[p].x = fmaf(hi, w[2 * p],     act[p].x);
            act[p].y = fmaf(hi, w[2 * p + 1], act[p].y);
        }
    }

    float2 hacc[16];
#pragma unroll
    for (int p = 0; p < 16; ++p) { hacc[p].x = 0.0f; hacc[p].y = 0.0f; }

    const int ks = off[n], ke = off[n + 1];
    int k = ks;
    for (; k + 1 < ke; k += 2) {
        const uint4* pa = a1 + (size_t)ids[k]     * 64 + b;
        const uint4* pb = a1 + (size_t)ids[k + 1] * 64 + b;
        uint4 qa0 = pa[0], qa1 = pa[16], qa2 = pa[32], qa3 = pa[48];
        uint4 qb0 = pb[0], qb1 = pb[16], qb2 = pb[32], qb3 = pb[48];
        consume_edge(qa0, qa1, qa2, qa3, act, hacc);
        consume_edge(qb0, qb1, qb2, qb3, act, hacc);
    }
    if (k < ke) {
        const uint4* pa = a1 + (size_t)ids[k] * 64 + b;
        consume_edge(pa[0], pa[16], pa[32], pa[48], act, hacc);
    }

    float m[D_MSG];
#pragma unroll
    for (int j = 0; j < D_MSG; ++j) m[j] = 0.0f;
#pragma unroll
    for (int p = 0; p < 16; ++p) {
        const float h0 = hacc[p].x, h1 = hacc[p].y;
        const float* w0 = W2 + (2 * p) * D_MSG;
        const float* w1 = W2 + (2 * p + 1) * D_MSG;
#pragma unroll
        for (int j = 0; j < D_MSG; ++j)
            m[j] = fmaf(h0, w0[j], fmaf(h1, w1[j], m[j]));
    }
#pragma unroll
    for (int j = 0; j < D_MSG; ++j) mout[j] = m[j];
}

// gather+node FUSED: thread=(n,b) computes both channel messages (kept fp32
// in registers, no bf16 round-trip) then applies the node MLP
// [m_x | m_z | h_to] -> 32 (relu) -> 16 and writes the final output directly.
// Eliminates node_kernel's 154 MB of HBM round-trip traffic + one launch.
__global__ __launch_bounds__(256, 4) void gather_node_kernel(
    const float* __restrict__ h_to,
    const int* __restrict__ off_x, const int* __restrict__ ids_x,
    const int* __restrict__ off_z, const int* __restrict__ ids_z,
    const uint4* __restrict__ a1x, const uint4* __restrict__ a1z,
    const float* __restrict__ Wx1, const float* __restrict__ Wx2,
    const float* __restrict__ Wz1, const float* __restrict__ Wz2,
    const float* __restrict__ We1, const float* __restrict__ We2,
    float* __restrict__ out)
{
    const int t = blockIdx.x * 256 + threadIdx.x;
    if (t >= NUM_VN * BATCH) return;
    const int b = t & (BATCH - 1);
    const int n = t >> 4;
    const size_t slot = (size_t)b * NUM_VN + n;
    const float* ht_slot = h_to + slot * D_EMBED;

    float mall[2 * D_MSG];
    channel_accum(ht_slot, n, b, off_x, ids_x, a1x, Wx1, Wx2, mall);
    channel_accum(ht_slot, n, b, off_z, ids_z, a1z, Wz1, Wz2, mall + D_MSG);

    // ---- node MLP: feat = [m_x(16) | m_z(16) | ht(16)] ----
    float2 hid[16];
#pragma unroll
    for (int p = 0; p < 16; ++p) { hid[p].x = 0.0f; hid[p].y = 0.0f; }
#pragma unroll
    for (int i = 0; i < 2 * D_MSG; ++i) {
        const float fi = mall[i];
        const float* w = We1 + i * D_HIDDEN;
#pragma unroll
        for (int p = 0; p < 16; ++p) {
            hid[p].x = fmaf(fi, w[2 * p],     hid[p].x);
            hid[p].y = fmaf(fi, w[2 * p + 1], hid[p].y);
        }
    }
    // ht rows 32..47 (reload: L1-hot)
#pragma unroll
    for (int i4 = 0; i4 < 4; ++i4) {
        float4 v = ((const float4*)ht_slot)[i4];
        float hv[4] = {v.x, v.y, v.z, v.w};
#pragma unroll
        for (int j = 0; j < 4; ++j) {
            const float fi = hv[j];
            const float* w = We1 + (2 * D_MSG + 4 * i4 + j) * D_HIDDEN;
#pragma unroll
            for (int p = 0; p < 16; ++p) {
                hid[p].x = fmaf(fi, w[2 * p],     hid[p].x);
                hid[p].y = fmaf(fi, w[2 * p + 1], hid[p].y);
            }
        }
    }
#pragma unroll
    for (int p = 0; p < 16; ++p) {
        hid[p].x = fmaxf(hid[p].x, 0.0f);
        hid[p].y = fmaxf(hid[p].y, 0.0f);
    }

    float o[D_EMBED];
#pragma unroll
    for (int kk = 0; kk < D_EMBED; ++kk) o[kk] = 0.0f;
#pragma unroll
    for (int p = 0; p < 16; ++p) {
        const float h0 = hid[p].x, h1 = hid[p].y;
        const float* w0 = We2 + (2 * p) * D_EMBED;
        const float* w1 = We2 + (2 * p + 1) * D_EMBED;
#pragma unroll
        for (int kk = 0; kk < D_EMBED; ++kk)
            o[kk] = fmaf(h0, w0[kk], fmaf(h1, w1[kk], o[kk]));
    }

#pragma unroll
    for (int i = 0; i < 4; ++i) {
        float4 v;
        v.x = o[4 * i + 0]; v.y = o[4 * i + 1];
        v.z = o[4 * i + 2]; v.w = o[4 * i + 3];
        ((float4*)(out + slot * D_EMBED))[i] = v;
    }
}

// ---------------------------------------------------------------------------
extern "C" void kernel_launch(void* const* d_in, const int* in_sizes, int n_in,
                              void* d_out, int out_size, void* d_ws, size_t ws_size,
                              hipStream_t stream) {
    const float* h_from_x = (const float*)d_in[0];
    const float* h_from_z = (const float*)d_in[1];
    const float* h_to     = (const float*)d_in[2];
    const int*   syn_x    = (const int*)d_in[3];
    const int*   syn_z    = (const int*)d_in[4];
    const int*   fi_x     = (const int*)d_in[5];
    const int*   ti_x     = (const int*)d_in[6];
    const int*   fi_z     = (const int*)d_in[7];
    const int*   ti_z     = (const int*)d_in[8];
    const float* Wx1      = (const float*)d_in[9];
    const float* Wx2      = (const float*)d_in[10];
    const float* Wz1      = (const float*)d_in[11];
    const float* Wz2      = (const float*)d_in[12];
    const float* We1      = (const float*)d_in[13];
    const float* We2      = (const float*)d_in[14];

    int* ws = (int*)d_ws;
    int* ids_x  = ws + WS_IDS_X;
    int* ids_z  = ws + WS_IDS_Z;
    int* off_x  = ws + WS_OFF_X;
    int* off_z  = ws + WS_OFF_Z;
    int* cnt_x  = ws + WS_CNT_X;
    int* cnt_z  = ws + WS_CNT_Z;
    int* cur_x  = ws + WS_CUR_X;
    int* cur_z  = ws + WS_CUR_Z;
    int* incl_x = ws + WS_INCL_X;
    int* incl_z = ws + WS_INCL_Z;
    int* psum   = ws + WS_PSUM;
    int* base   = ws + WS_BASE;
    uint4* a1x  = (uint4*)(ws + WS_A1X);
    uint4* a1z  = (uint4*)(ws + WS_A1Z);

    // cur_* are dead after fill -> reuse as syndrome bitmasks
    unsigned* bits_x = (unsigned*)cur_x;
    unsigned* bits_z = (unsigned*)cur_z;

    hipMemsetAsync(cnt_x, 0, 2 * NUM_VN * sizeof(int), stream);

    hist_kernel<<<dim3((NUM_E + 255) / 256), dim3(256), 0, stream>>>(
        ti_x, ti_z, cnt_x, cnt_z);
    scan1_kernel<<<dim3(SCAN_CHUNKS, 2), dim3(1024), 0, stream>>>(
        cnt_x, cnt_z, incl_x, incl_z, psum);
    scan2_kernel<<<dim3(1), dim3(64), 0, stream>>>(psum, base);
    scan3_kernel<<<dim3(SCAN_CHUNKS, 2), dim3(1024), 0, stream>>>(
        cnt_x, cnt_z, incl_x, incl_z, base, off_x, off_z, cur_x, cur_z);
    fill_kernel<<<dim3((NUM_E + 255) / 256), dim3(256), 0, stream>>>(
        ti_x, ti_z, fi_x, fi_z, cur_x, cur_z, ids_x, ids_z);
    pack_bits_kernel<<<dim3((NUM_CN + 255) / 256), dim3(256), 0, stream>>>(
        syn_x, syn_z, bits_x, bits_z);

    a1_kernel<<<dim3((NUM_CN * BATCH + 255) / 256, 2), dim3(256), 0, stream>>>(
        h_from_x, h_from_z, Wx1, Wz1, bits_x, bits_z, a1x, a1z);

    gather_node_kernel<<<dim3((NUM_VN * BATCH) / 256), dim3(256), 0, stream>>>(
        h_to, off_x, ids_x, off_z, ids_z, a1x, a1z,
        Wx1, Wx2, Wz1, Wz2, We1, We2, (float*)d_out);
}